// Round 1
// baseline (108.735 us; speedup 1.0000x reference)
//
#include <hip/hip_runtime.h>
#include <hip/hip_bf16.h>

// ---------------------------------------------------------------------------
// Fused attention: x@Wqkv -> q,k,v ; flash split-KV attention over
// concat(past_k, k_new) ; combine ; @Wproj -> out.
// B=2, N=256, DIM=1024, H=16, D=64, L=8192, total keys 8448.
// All MFMA in bf16 (16x16x32), f32 accumulate. KV read once (f32, 268MB).
// ---------------------------------------------------------------------------

#define BB 2
#define NH 16
#define NQ 256
#define HD 64
#define DIMC 1024
#define LPAST 8192
#define TOTK 8448
#define NSPLIT 16
#define CHUNK 528   // 8448 / 16; 8 full 64-key steps + one 16-key step

typedef __attribute__((ext_vector_type(8))) short short8;
typedef __attribute__((ext_vector_type(4))) float f32x4;

#define DEVI static __device__ __forceinline__

DEVI short f2bf(float f) {               // f32 -> bf16 (RNE)
  union { float f; unsigned u; } v; v.f = f;
  unsigned r = v.u + 0x7FFFu + ((v.u >> 16) & 1u);
  return (short)(r >> 16);
}
DEVI short f2h(float f) {                // f32 -> f16 bits
  _Float16 h = (_Float16)f;
  return __builtin_bit_cast(short, h);
}
DEVI float h2f(short s) {
  return (float)__builtin_bit_cast(_Float16, s);
}

// ---------------------------------------------------------------------------
// Generic 64x64-tile bf16 MFMA GEMM, f32 inputs converted during staging.
// MODE 0: Cout[row*Nn+col] = acc + bias[col]
// MODE 1: scatter into q (bf16, *0.125), k_new, v_new  [B,H,N,D]
// ---------------------------------------------------------------------------
template<int MODE>
__global__ __launch_bounds__(256, 2) void gemm_k(
    const float* __restrict__ A, const float* __restrict__ Bm,
    const float* __restrict__ bias, float* __restrict__ Cout,
    short* __restrict__ qbuf, float* __restrict__ knew, float* __restrict__ vnew,
    int M, int Nn, int K)
{
  __shared__ alignas(16) short As[64][72];   // [m][k] bf16, +8 pad
  __shared__ alignas(16) short Bs[64][72];   // [n][k] bf16 (B transposed)
  const int tid = threadIdx.x;
  const int lane = tid & 63, wave = tid >> 6;
  const int nblk = Nn >> 6;
  const int bi = blockIdx.x / nblk, bj = blockIdx.x % nblk;
  const int wm = wave >> 1, wn = wave & 1;
  const int g = lane >> 4, l16 = lane & 15;
  f32x4 acc[2][2] = {};
  const int r = tid >> 2, q4 = (tid & 3) << 4;   // staging: row r, 16 elems @ q4

  for (int k0 = 0; k0 < K; k0 += 64) {
    const float* pa = A + (size_t)(bi * 64 + r) * K + (k0 + q4);
    float4 a0 = ((const float4*)pa)[0];
    float4 a1 = ((const float4*)pa)[1];
    float4 a2 = ((const float4*)pa)[2];
    float4 a3 = ((const float4*)pa)[3];
    const float* pb = Bm + (size_t)(k0 + r) * Nn + (bj * 64 + q4);
    float4 b0 = ((const float4*)pb)[0];
    float4 b1 = ((const float4*)pb)[1];
    float4 b2 = ((const float4*)pb)[2];
    float4 b3 = ((const float4*)pb)[3];
    __syncthreads();
    short8 av0 = {f2bf(a0.x),f2bf(a0.y),f2bf(a0.z),f2bf(a0.w),
                  f2bf(a1.x),f2bf(a1.y),f2bf(a1.z),f2bf(a1.w)};
    short8 av1 = {f2bf(a2.x),f2bf(a2.y),f2bf(a2.z),f2bf(a2.w),
                  f2bf(a3.x),f2bf(a3.y),f2bf(a3.z),f2bf(a3.w)};
    *(short8*)&As[r][q4]     = av0;
    *(short8*)&As[r][q4 + 8] = av1;
    // B transposed into Bs[n][k]
    Bs[q4+ 0][r] = f2bf(b0.x); Bs[q4+ 1][r] = f2bf(b0.y);
    Bs[q4+ 2][r] = f2bf(b0.z); Bs[q4+ 3][r] = f2bf(b0.w);
    Bs[q4+ 4][r] = f2bf(b1.x); Bs[q4+ 5][r] = f2bf(b1.y);
    Bs[q4+ 6][r] = f2bf(b1.z); Bs[q4+ 7][r] = f2bf(b1.w);
    Bs[q4+ 8][r] = f2bf(b2.x); Bs[q4+ 9][r] = f2bf(b2.y);
    Bs[q4+10][r] = f2bf(b2.z); Bs[q4+11][r] = f2bf(b2.w);
    Bs[q4+12][r] = f2bf(b3.x); Bs[q4+13][r] = f2bf(b3.y);
    Bs[q4+14][r] = f2bf(b3.z); Bs[q4+15][r] = f2bf(b3.w);
    __syncthreads();
    #pragma unroll
    for (int kf = 0; kf < 2; ++kf) {
      short8 af[2], bfv[2];
      #pragma unroll
      for (int mt = 0; mt < 2; ++mt)
        af[mt] = *(const short8*)&As[wm*32 + mt*16 + l16][kf*32 + g*8];
      #pragma unroll
      for (int nt = 0; nt < 2; ++nt)
        bfv[nt] = *(const short8*)&Bs[wn*32 + nt*16 + l16][kf*32 + g*8];
      #pragma unroll
      for (int mt = 0; mt < 2; ++mt)
        #pragma unroll
        for (int nt = 0; nt < 2; ++nt)
          acc[mt][nt] = __builtin_amdgcn_mfma_f32_16x16x32_bf16(
              af[mt], bfv[nt], acc[mt][nt], 0, 0, 0);
    }
  }

  #pragma unroll
  for (int mt = 0; mt < 2; ++mt)
    #pragma unroll
    for (int nt = 0; nt < 2; ++nt)
      #pragma unroll
      for (int rg = 0; rg < 4; ++rg) {
        int row = bi*64 + wm*32 + mt*16 + g*4 + rg;
        int col = bj*64 + wn*32 + nt*16 + l16;
        float val = acc[mt][nt][rg] + bias[col];
        if (MODE == 0) {
          Cout[(size_t)row * Nn + col] = val;
        } else {
          int which = col >> 10, cc = col & 1023;
          int h = cc >> 6, d = cc & 63;
          int b = row >> 8, n = row & 255;
          size_t idx = (((size_t)(b*NH + h))*NQ + n)*HD + d;
          if (which == 0)      qbuf[idx] = f2bf(val * 0.125f);  // fold softmax scale
          else if (which == 1) knew[idx] = val;
          else                 vnew[idx] = val;
        }
      }
}

// ---------------------------------------------------------------------------
// Flash attention, split-KV. Grid: (B*H) * NSPLIT blocks, 256 threads.
// Per block: 4 waves x 64 query rows; chunk of CHUNK keys in 64-key steps.
// ---------------------------------------------------------------------------
__global__ __launch_bounds__(256, 2) void attn_k(
    const short* __restrict__ qbuf, const float* __restrict__ pastk,
    const float* __restrict__ pastv, const float* __restrict__ knew,
    const float* __restrict__ vnew, float* __restrict__ opart,
    float* __restrict__ mbuf, float* __restrict__ lbuf)
{
  __shared__ alignas(16) short Kt[64][72];   // [key][d]  bf16
  __shared__ alignas(16) short Vt[64][72];   // [d][key]  bf16 (transposed)
  __shared__ alignas(16) short Sb[256][72];  // scores f16 -> P bf16
  __shared__ float alphaB[256];
  const int tid = threadIdx.x;
  const int lane = tid & 63, wave = tid >> 6;
  const int g = lane >> 4, l16 = lane & 15;
  const int s = blockIdx.x & (NSPLIT - 1), bh = blockIdx.x / NSPLIT;

  // Q fragments in registers (already scaled by 0.125 at QKV epilogue)
  short8 qf[4][2];
  #pragma unroll
  for (int mt = 0; mt < 4; ++mt)
    #pragma unroll
    for (int kf = 0; kf < 2; ++kf)
      qf[mt][kf] = *(const short8*)(qbuf +
          ((size_t)bh*NQ + wave*64 + mt*16 + l16)*HD + kf*32 + g*8);

  f32x4 acc[4][4] = {};
  float m_t = -INFINITY, l_t = 0.f;
  const int r = tid >> 2, q4 = (tid & 3) << 4;
  const int start = s * CHUNK, end = start + CHUNK;

  for (int k0 = start; k0 < end; k0 += 64) {
    const int valid = min(64, end - k0);
    const int l = k0 + r;
    float4 kv[4], vv[4];
    #pragma unroll
    for (int j = 0; j < 4; ++j) {
      kv[j] = make_float4(0.f,0.f,0.f,0.f);
      vv[j] = make_float4(0.f,0.f,0.f,0.f);
    }
    if (l < TOTK) {
      const float *kp, *vp;
      if (l < LPAST) {
        size_t off = ((size_t)bh * LPAST + l) * HD + q4;
        kp = pastk + off; vp = pastv + off;
      } else {
        size_t off = ((size_t)bh * NQ + (l - LPAST)) * HD + q4;
        kp = knew + off; vp = vnew + off;
      }
      #pragma unroll
      for (int j = 0; j < 4; ++j) {
        kv[j] = ((const float4*)kp)[j];
        vv[j] = ((const float4*)vp)[j];
      }
    }
    __syncthreads();   // previous iteration done reading LDS
    {
      short8 c0 = {f2bf(kv[0].x),f2bf(kv[0].y),f2bf(kv[0].z),f2bf(kv[0].w),
                   f2bf(kv[1].x),f2bf(kv[1].y),f2bf(kv[1].z),f2bf(kv[1].w)};
      short8 c1 = {f2bf(kv[2].x),f2bf(kv[2].y),f2bf(kv[2].z),f2bf(kv[2].w),
                   f2bf(kv[3].x),f2bf(kv[3].y),f2bf(kv[3].z),f2bf(kv[3].w)};
      *(short8*)&Kt[r][q4]     = c0;
      *(short8*)&Kt[r][q4 + 8] = c1;
      const float* vvf = (const float*)vv;
      #pragma unroll
      for (int j = 0; j < 16; ++j) Vt[q4 + j][r] = f2bf(vvf[j]);
    }
    __syncthreads();

    // S = Q K^T  (per wave: 64 rows x 64 keys)
    for (int nt = 0; nt < 4; ++nt) {
      short8 kf0 = *(const short8*)&Kt[nt*16 + l16][g*8];
      short8 kf1 = *(const short8*)&Kt[nt*16 + l16][32 + g*8];
      #pragma unroll
      for (int mt = 0; mt < 4; ++mt) {
        f32x4 sv = {};
        sv = __builtin_amdgcn_mfma_f32_16x16x32_bf16(qf[mt][0], kf0, sv, 0,0,0);
        sv = __builtin_amdgcn_mfma_f32_16x16x32_bf16(qf[mt][1], kf1, sv, 0,0,0);
        int row = wave*64 + mt*16 + g*4;
        int col = nt*16 + l16;
        #pragma unroll
        for (int rg = 0; rg < 4; ++rg) Sb[row + rg][col] = f2h(sv[rg]);
      }
    }
    __syncthreads();

    // Online softmax: thread t owns query row t
    {
      float mx = -INFINITY;
      const int nch = valid >> 3;
      for (int j = 0; j < nch; ++j) {
        short8 sc = *(const short8*)&Sb[tid][j*8];
        #pragma unroll
        for (int e = 0; e < 8; ++e) mx = fmaxf(mx, h2f(sc[e]));
      }
      float m_new = fmaxf(m_t, mx);
      float alpha = __expf(m_t - m_new);
      float ssum = 0.f;
      for (int j = 0; j < nch; ++j) {
        short8 sc = *(const short8*)&Sb[tid][j*8];
        short8 pb;
        #pragma unroll
        for (int e = 0; e < 8; ++e) {
          float p = __expf(h2f(sc[e]) - m_new);
          ssum += p;
          pb[e] = f2bf(p);
        }
        *(short8*)&Sb[tid][j*8] = pb;
      }
      for (int j = nch; j < 8; ++j) {
        short8 z = {};
        *(short8*)&Sb[tid][j*8] = z;
      }
      l_t = l_t * alpha + ssum;
      m_t = m_new;
      alphaB[tid] = alpha;
    }
    __syncthreads();

    // Rescale O, then O += P V
    #pragma unroll
    for (int mt = 0; mt < 4; ++mt)
      #pragma unroll
      for (int rg = 0; rg < 4; ++rg) {
        float a = alphaB[wave*64 + mt*16 + g*4 + rg];
        #pragma unroll
        for (int nt = 0; nt < 4; ++nt) acc[mt][nt][rg] *= a;
      }
    #pragma unroll
    for (int kf = 0; kf < 2; ++kf) {
      short8 vf[4];
      #pragma unroll
      for (int nt = 0; nt < 4; ++nt)
        vf[nt] = *(const short8*)&Vt[nt*16 + l16][kf*32 + g*8];
      #pragma unroll
      for (int mt = 0; mt < 4; ++mt) {
        short8 pf = *(const short8*)&Sb[wave*64 + mt*16 + l16][kf*32 + g*8];
        #pragma unroll
        for (int nt = 0; nt < 4; ++nt)
          acc[mt][nt] = __builtin_amdgcn_mfma_f32_16x16x32_bf16(
              pf, vf[nt], acc[mt][nt], 0,0,0);
      }
    }
  }

  // Write partials
  size_t pbase = ((size_t)(bh * NSPLIT + s)) * NQ;
  #pragma unroll
  for (int mt = 0; mt < 4; ++mt)
    #pragma unroll
    for (int nt = 0; nt < 4; ++nt)
      #pragma unroll
      for (int rg = 0; rg < 4; ++rg) {
        int row = wave*64 + mt*16 + g*4 + rg;
        int col = nt*16 + l16;
        opart[(pbase + row)*HD + col] = acc[mt][nt][rg];
      }
  mbuf[pbase + tid] = m_t;
  lbuf[pbase + tid] = l_t;
}

// ---------------------------------------------------------------------------
// Combine NSPLIT partials per (b,h,n); write attn output [B,N,DIM] f32
// ---------------------------------------------------------------------------
__global__ __launch_bounds__(256) void combine_k(
    const float* __restrict__ opart, const float* __restrict__ mbuf,
    const float* __restrict__ lbuf, float* __restrict__ attnout)
{
  const int lane = threadIdx.x & 63, wave = threadIdx.x >> 6;
  const int rid = blockIdx.x * 4 + wave;   // 0 .. B*H*N-1
  const int bh = rid >> 8, n = rid & 255;
  const int b = bh >> 4, h = bh & 15;
  float M = -INFINITY;
  float ms[NSPLIT], ls[NSPLIT];
  #pragma unroll
  for (int s = 0; s < NSPLIT; ++s) {
    size_t base = ((size_t)(bh * NSPLIT + s)) * NQ + n;
    ms[s] = mbuf[base]; ls[s] = lbuf[base];
    M = fmaxf(M, ms[s]);
  }
  float denom = 0.f, o = 0.f;
  #pragma unroll
  for (int s = 0; s < NSPLIT; ++s) {
    float w = __expf(ms[s] - M);
    denom += w * ls[s];
    o += w * opart[(((size_t)(bh * NSPLIT + s)) * NQ + n) * HD + lane];
  }
  attnout[((size_t)(b * NQ + n)) * DIMC + h * HD + lane] = o / denom;
}

// ---------------------------------------------------------------------------
extern "C" void kernel_launch(void* const* d_in, const int* in_sizes, int n_in,
                              void* d_out, int out_size, void* d_ws, size_t ws_size,
                              hipStream_t stream)
{
  const float* x     = (const float*)d_in[0];
  const float* pastk = (const float*)d_in[1];
  const float* pastv = (const float*)d_in[2];
  const float* wqkv  = (const float*)d_in[3];
  const float* bqkv  = (const float*)d_in[4];
  const float* wproj = (const float*)d_in[5];
  const float* bproj = (const float*)d_in[6];
  float* out = (float*)d_out;
  char* ws = (char*)d_ws;

  size_t off = 0;
  short* qbuf   = (short*)(ws + off); off += (size_t)BB*NH*NQ*HD*2;          // 1MB
  float* knew   = (float*)(ws + off); off += (size_t)BB*NH*NQ*HD*4;          // 2MB
  float* vnew   = (float*)(ws + off); off += (size_t)BB*NH*NQ*HD*4;          // 2MB
  float* opart  = (float*)(ws + off); off += (size_t)BB*NH*NSPLIT*NQ*HD*4;   // 32MB
  float* mbuf   = (float*)(ws + off); off += (size_t)BB*NH*NSPLIT*NQ*4;      // 512KB
  float* lbuf   = (float*)(ws + off); off += (size_t)BB*NH*NSPLIT*NQ*4;      // 512KB
  float* attnout= (float*)(ws + off); off += (size_t)BB*NQ*DIMC*4;           // 2MB

  // 1) QKV projection: [512,1024] x [1024,3072]
  gemm_k<1><<<(512/64)*(3072/64), 256, 0, stream>>>(
      x, wqkv, bqkv, nullptr, qbuf, knew, vnew, 512, 3072, 1024);
  // 2) split-KV flash attention
  attn_k<<<BB*NH*NSPLIT, 256, 0, stream>>>(
      qbuf, pastk, pastv, knew, vnew, opart, mbuf, lbuf);
  // 3) combine partials
  combine_k<<<BB*NH*NQ/4, 256, 0, stream>>>(opart, mbuf, lbuf, attnout);
  // 4) output projection: [512,1024] x [1024,1024]
  gemm_k<0><<<(512/64)*(1024/64), 256, 0, stream>>>(
      attnout, wproj, bproj, out, nullptr, nullptr, nullptr, 512, 1024, 1024);
}

// Round 2
// 94.643 us; speedup vs baseline: 1.1489x; 1.1489x over previous
//
#include <hip/hip_runtime.h>
#include <hip/hip_bf16.h>

// ---------------------------------------------------------------------------
// Fused attention: x@Wqkv -> q,k,v ; flash split-KV attention over
// concat(past_k, k_new) ; combine ; @Wproj -> out.
// B=2, N=256, DIM=1024, H=16, D=64, L=8192, total keys 8448 = 132 x 64.
// R2: swapped-QK (S^T = K*Q^T) in-register online softmax; P lands directly
// in PV A-fragment layout via k-permutation freedom (no score LDS roundtrip).
// ---------------------------------------------------------------------------

#define BB 2
#define NH 16
#define NQ 256
#define HD 64
#define DIMC 1024
#define LPAST 8192
#define TOTK 8448
#define NSPLIT 16
// 132 total 64-key steps; split s gets 8+(s<4) steps starting at 8*s+min(s,4)

typedef __attribute__((ext_vector_type(8))) short short8;
typedef __attribute__((ext_vector_type(4))) float f32x4;
typedef __attribute__((ext_vector_type(4))) int int4v;

#define DEVI static __device__ __forceinline__

DEVI short f2bf(float f) {               // f32 -> bf16 (RNE)
  union { float f; unsigned u; } v; v.f = f;
  unsigned r = v.u + 0x7FFFu + ((v.u >> 16) & 1u);
  return (short)(r >> 16);
}

// ---------------------------------------------------------------------------
// Generic 64x64-tile bf16 MFMA GEMM, f32 inputs converted during staging.
// MODE 0: Cout[row*Nn+col] = acc + bias[col]
// MODE 1: scatter into q (bf16, *0.125), k_new, v_new  [B,H,N,D]
// ---------------------------------------------------------------------------
template<int MODE>
__global__ __launch_bounds__(256, 2) void gemm_k(
    const float* __restrict__ A, const float* __restrict__ Bm,
    const float* __restrict__ bias, float* __restrict__ Cout,
    short* __restrict__ qbuf, float* __restrict__ knew, float* __restrict__ vnew,
    int M, int Nn, int K)
{
  __shared__ alignas(16) short As[64][72];   // [m][k] bf16, +8 pad
  __shared__ alignas(16) short Bs[64][72];   // [n][k] bf16 (B transposed)
  const int tid = threadIdx.x;
  const int lane = tid & 63, wave = tid >> 6;
  const int nblk = Nn >> 6;
  const int bi = blockIdx.x / nblk, bj = blockIdx.x % nblk;
  const int wm = wave >> 1, wn = wave & 1;
  const int g = lane >> 4, l16 = lane & 15;
  f32x4 acc[2][2] = {};
  const int r = tid >> 2, q4 = (tid & 3) << 4;   // staging: row r, 16 elems @ q4

  for (int k0 = 0; k0 < K; k0 += 64) {
    const float* pa = A + (size_t)(bi * 64 + r) * K + (k0 + q4);
    float4 a0 = ((const float4*)pa)[0];
    float4 a1 = ((const float4*)pa)[1];
    float4 a2 = ((const float4*)pa)[2];
    float4 a3 = ((const float4*)pa)[3];
    const float* pb = Bm + (size_t)(k0 + r) * Nn + (bj * 64 + q4);
    float4 b0 = ((const float4*)pb)[0];
    float4 b1 = ((const float4*)pb)[1];
    float4 b2 = ((const float4*)pb)[2];
    float4 b3 = ((const float4*)pb)[3];
    __syncthreads();
    short8 av0 = {f2bf(a0.x),f2bf(a0.y),f2bf(a0.z),f2bf(a0.w),
                  f2bf(a1.x),f2bf(a1.y),f2bf(a1.z),f2bf(a1.w)};
    short8 av1 = {f2bf(a2.x),f2bf(a2.y),f2bf(a2.z),f2bf(a2.w),
                  f2bf(a3.x),f2bf(a3.y),f2bf(a3.z),f2bf(a3.w)};
    *(short8*)&As[r][q4]     = av0;
    *(short8*)&As[r][q4 + 8] = av1;
    Bs[q4+ 0][r] = f2bf(b0.x); Bs[q4+ 1][r] = f2bf(b0.y);
    Bs[q4+ 2][r] = f2bf(b0.z); Bs[q4+ 3][r] = f2bf(b0.w);
    Bs[q4+ 4][r] = f2bf(b1.x); Bs[q4+ 5][r] = f2bf(b1.y);
    Bs[q4+ 6][r] = f2bf(b1.z); Bs[q4+ 7][r] = f2bf(b1.w);
    Bs[q4+ 8][r] = f2bf(b2.x); Bs[q4+ 9][r] = f2bf(b2.y);
    Bs[q4+10][r] = f2bf(b2.z); Bs[q4+11][r] = f2bf(b2.w);
    Bs[q4+12][r] = f2bf(b3.x); Bs[q4+13][r] = f2bf(b3.y);
    Bs[q4+14][r] = f2bf(b3.z); Bs[q4+15][r] = f2bf(b3.w);
    __syncthreads();
    #pragma unroll
    for (int kf = 0; kf < 2; ++kf) {
      short8 af[2], bfv[2];
      #pragma unroll
      for (int mt = 0; mt < 2; ++mt)
        af[mt] = *(const short8*)&As[wm*32 + mt*16 + l16][kf*32 + g*8];
      #pragma unroll
      for (int nt = 0; nt < 2; ++nt)
        bfv[nt] = *(const short8*)&Bs[wn*32 + nt*16 + l16][kf*32 + g*8];
      #pragma unroll
      for (int mt = 0; mt < 2; ++mt)
        #pragma unroll
        for (int nt = 0; nt < 2; ++nt)
          acc[mt][nt] = __builtin_amdgcn_mfma_f32_16x16x32_bf16(
              af[mt], bfv[nt], acc[mt][nt], 0, 0, 0);
    }
  }

  #pragma unroll
  for (int mt = 0; mt < 2; ++mt)
    #pragma unroll
    for (int nt = 0; nt < 2; ++nt)
      #pragma unroll
      for (int rg = 0; rg < 4; ++rg) {
        int row = bi*64 + wm*32 + mt*16 + g*4 + rg;
        int col = bj*64 + wn*32 + nt*16 + l16;
        float val = acc[mt][nt][rg] + bias[col];
        if (MODE == 0) {
          Cout[(size_t)row * Nn + col] = val;
        } else {
          int which = col >> 10, cc = col & 1023;
          int h = cc >> 6, d = cc & 63;
          int b = row >> 8, n = row & 255;
          size_t idx = (((size_t)(b*NH + h))*NQ + n)*HD + d;
          if (which == 0)      qbuf[idx] = f2bf(val * 0.125f);  // fold softmax scale
          else if (which == 1) knew[idx] = val;
          else                 vnew[idx] = val;
        }
      }
}

// ---------------------------------------------------------------------------
// Flash attention, split-KV, swapped-QK in-register softmax.
// Grid: (B*H)*NSPLIT blocks, 256 threads = 4 waves x 64 queries.
// Per 64-key step: S^T = mfma(K_frag, Q_frag); each lane holds 16 scores for
// query q = qt*16+l16, keys kt*16+g*4+rg. Softmax reduce = 2 shfl_xor.
// P is already the PV A-fragment under key permutation
//   sigma(g,j,kk) = 4g + (j&3) + 16*(j>>2) + 32kk,
// matched on the B side by reading Vt[d][sigma] (transposed V in LDS).
// ---------------------------------------------------------------------------
__global__ __launch_bounds__(256, 2) void attn_k(
    const short* __restrict__ qbuf, const float* __restrict__ pastk,
    const float* __restrict__ pastv, const float* __restrict__ knew,
    const float* __restrict__ vnew, float* __restrict__ opart,
    float* __restrict__ mbuf, float* __restrict__ lbuf)
{
  __shared__ alignas(16) short Kt[64][72];   // [key][d]  bf16, b128-friendly
  __shared__ alignas(16) short Vt[64][66];   // [d][key]  bf16, odd-dword stride
  const int tid = threadIdx.x;
  const int lane = tid & 63, wave = tid >> 6;
  const int g = lane >> 4, l16 = lane & 15;
  const int s = blockIdx.x & (NSPLIT - 1), bh = blockIdx.x / NSPLIT;
  const int r = tid >> 2, q4 = (tid & 3) << 4;

  // Q fragments (B-operand of S^T): lane holds Q[q=qt*16+l16][d=half*32+g*8..+7]
  short8 qf[4][2];
  #pragma unroll
  for (int qt = 0; qt < 4; ++qt)
    #pragma unroll
    for (int half = 0; half < 2; ++half)
      qf[qt][half] = *(const short8*)(qbuf +
          ((size_t)bh*NQ + wave*64 + qt*16 + l16)*HD + half*32 + g*8);

  f32x4 acc[4][4] = {};     // acc[qt][dt]: q = qt*16+g*4+rg, d = dt*16+l16
  float m_s[4], l_s[4];
  #pragma unroll
  for (int qt = 0; qt < 4; ++qt) { m_s[qt] = -INFINITY; l_s[qt] = 0.f; }

  const int first = 8*s + (s < 4 ? s : 4);
  const int nsteps = 8 + (s < 4 ? 1 : 0);

  float4 kv[4], vv[4];
  {  // prefetch step `first`
    int l = first*64 + r;
    const float *kp, *vp;
    if (l < LPAST) { size_t off = ((size_t)bh*LPAST + l)*HD + q4; kp = pastk + off; vp = pastv + off; }
    else           { size_t off = ((size_t)bh*NQ + (l - LPAST))*HD + q4; kp = knew + off; vp = vnew + off; }
    #pragma unroll
    for (int j = 0; j < 4; ++j) { kv[j] = ((const float4*)kp)[j]; vv[j] = ((const float4*)vp)[j]; }
  }

  for (int it = 0; it < nsteps; ++it) {
    __syncthreads();   // previous step's LDS reads complete
    {
      const float* kvf = (const float*)kv;
      short8 c0 = {f2bf(kvf[0]),f2bf(kvf[1]),f2bf(kvf[2]),f2bf(kvf[3]),
                   f2bf(kvf[4]),f2bf(kvf[5]),f2bf(kvf[6]),f2bf(kvf[7])};
      short8 c1 = {f2bf(kvf[8]),f2bf(kvf[9]),f2bf(kvf[10]),f2bf(kvf[11]),
                   f2bf(kvf[12]),f2bf(kvf[13]),f2bf(kvf[14]),f2bf(kvf[15])};
      *(short8*)&Kt[r][q4]     = c0;
      *(short8*)&Kt[r][q4 + 8] = c1;
      const float* vvf = (const float*)vv;
      #pragma unroll
      for (int jj = 0; jj < 16; ++jj) Vt[q4 + jj][r] = f2bf(vvf[jj]);
    }
    __syncthreads();

    if (it + 1 < nsteps) {   // issue next step's loads; latency hides under compute
      int l = (first + it + 1)*64 + r;
      const float *kp, *vp;
      if (l < LPAST) { size_t off = ((size_t)bh*LPAST + l)*HD + q4; kp = pastk + off; vp = pastv + off; }
      else           { size_t off = ((size_t)bh*NQ + (l - LPAST))*HD + q4; kp = knew + off; vp = vnew + off; }
      #pragma unroll
      for (int j = 0; j < 4; ++j) { kv[j] = ((const float4*)kp)[j]; vv[j] = ((const float4*)vp)[j]; }
    }

    // K fragments (A-operand of S^T): row = key = kt*16+l16, d = half*32+g*8
    short8 kf[4][2];
    #pragma unroll
    for (int kt = 0; kt < 4; ++kt)
      #pragma unroll
      for (int half = 0; half < 2; ++half)
        kf[kt][half] = *(const short8*)&Kt[kt*16 + l16][half*32 + g*8];

    short8 pa[4][2];
    #pragma unroll
    for (int qt = 0; qt < 4; ++qt) {
      f32x4 sv[4];
      #pragma unroll
      for (int kt = 0; kt < 4; ++kt) {
        f32x4 z = {0.f, 0.f, 0.f, 0.f};
        z = __builtin_amdgcn_mfma_f32_16x16x32_bf16(kf[kt][0], qf[qt][0], z, 0,0,0);
        sv[kt] = __builtin_amdgcn_mfma_f32_16x16x32_bf16(kf[kt][1], qf[qt][1], z, 0,0,0);
      }
      // in-lane max over 16 scores, then across the 4 lane-groups
      float mx = sv[0][0];
      #pragma unroll
      for (int kt = 0; kt < 4; ++kt)
        #pragma unroll
        for (int rg = 0; rg < 4; ++rg) mx = fmaxf(mx, sv[kt][rg]);
      mx = fmaxf(mx, __shfl_xor(mx, 16));
      mx = fmaxf(mx, __shfl_xor(mx, 32));
      float m_new = fmaxf(m_s[qt], mx);
      float al = __expf(m_s[qt] - m_new);
      float ss = 0.f;
      #pragma unroll
      for (int kt = 0; kt < 4; ++kt)
        #pragma unroll
        for (int rg = 0; rg < 4; ++rg) {
          float p = __expf(sv[kt][rg] - m_new);
          sv[kt][rg] = p; ss += p;
        }
      ss += __shfl_xor(ss, 16);
      ss += __shfl_xor(ss, 32);
      l_s[qt] = l_s[qt]*al + ss;
      m_s[qt] = m_new;
      // rescale O rows of this qt (acc rows are q = g*4+rg; alpha lives at lane q)
      #pragma unroll
      for (int rg = 0; rg < 4; ++rg) {
        float a = __shfl(al, g*4 + rg);
        #pragma unroll
        for (int dt = 0; dt < 4; ++dt) acc[qt][dt][rg] *= a;
      }
      // pack P into PV A-fragments: slot j (kk half) <- sv[2*kk + (j>>2)][j&3]
      pa[qt][0] = short8{f2bf(sv[0][0]),f2bf(sv[0][1]),f2bf(sv[0][2]),f2bf(sv[0][3]),
                         f2bf(sv[1][0]),f2bf(sv[1][1]),f2bf(sv[1][2]),f2bf(sv[1][3])};
      pa[qt][1] = short8{f2bf(sv[2][0]),f2bf(sv[2][1]),f2bf(sv[2][2]),f2bf(sv[2][3]),
                         f2bf(sv[3][0]),f2bf(sv[3][1]),f2bf(sv[3][2]),f2bf(sv[3][3])};
    }

    // PV: B-frag slot j <- Vt[d][32kk + 16*(j>>2) + 4g + (j&3)]
    #pragma unroll
    for (int kk = 0; kk < 2; ++kk) {
      short8 vf[4];
      #pragma unroll
      for (int dt = 0; dt < 4; ++dt) {
        const short* vrow = &Vt[dt*16 + l16][kk*32 + 4*g];
        int i0 = *(const int*)(vrow);
        int i1 = *(const int*)(vrow + 2);
        int i2 = *(const int*)(vrow + 16);
        int i3 = *(const int*)(vrow + 18);
        int4v iv = {i0, i1, i2, i3};
        vf[dt] = __builtin_bit_cast(short8, iv);
      }
      #pragma unroll
      for (int qt = 0; qt < 4; ++qt)
        #pragma unroll
        for (int dt = 0; dt < 4; ++dt)
          acc[qt][dt] = __builtin_amdgcn_mfma_f32_16x16x32_bf16(
              pa[qt][kk], vf[dt], acc[qt][dt], 0,0,0);
    }
  }

  // Write partials
  size_t pbase = ((size_t)(bh * NSPLIT + s)) * NQ;
  #pragma unroll
  for (int qt = 0; qt < 4; ++qt)
    #pragma unroll
    for (int dt = 0; dt < 4; ++dt)
      #pragma unroll
      for (int rg = 0; rg < 4; ++rg) {
        int row = wave*64 + qt*16 + g*4 + rg;
        int col = dt*16 + l16;
        opart[(pbase + row)*HD + col] = acc[qt][dt][rg];
      }
  if (g == 0) {
    #pragma unroll
    for (int qt = 0; qt < 4; ++qt) {
      int q = wave*64 + qt*16 + l16;
      mbuf[pbase + q] = m_s[qt];
      lbuf[pbase + q] = l_s[qt];
    }
  }
}

// ---------------------------------------------------------------------------
// Combine NSPLIT partials per (b,h,n); write attn output [B,N,DIM] f32
// ---------------------------------------------------------------------------
__global__ __launch_bounds__(256) void combine_k(
    const float* __restrict__ opart, const float* __restrict__ mbuf,
    const float* __restrict__ lbuf, float* __restrict__ attnout)
{
  const int lane = threadIdx.x & 63, wave = threadIdx.x >> 6;
  const int rid = blockIdx.x * 4 + wave;   // 0 .. B*H*N-1
  const int bh = rid >> 8, n = rid & 255;
  const int b = bh >> 4, h = bh & 15;
  float M = -INFINITY;
  float ms[NSPLIT], ls[NSPLIT];
  #pragma unroll
  for (int s = 0; s < NSPLIT; ++s) {
    size_t base = ((size_t)(bh * NSPLIT + s)) * NQ + n;
    ms[s] = mbuf[base]; ls[s] = lbuf[base];
    M = fmaxf(M, ms[s]);
  }
  float denom = 0.f, o = 0.f;
  #pragma unroll
  for (int s = 0; s < NSPLIT; ++s) {
    float w = __expf(ms[s] - M);
    denom += w * ls[s];
    o += w * opart[(((size_t)(bh * NSPLIT + s)) * NQ + n) * HD + lane];
  }
  attnout[((size_t)(b * NQ + n)) * DIMC + h * HD + lane] = o / denom;
}

// ---------------------------------------------------------------------------
extern "C" void kernel_launch(void* const* d_in, const int* in_sizes, int n_in,
                              void* d_out, int out_size, void* d_ws, size_t ws_size,
                              hipStream_t stream)
{
  const float* x     = (const float*)d_in[0];
  const float* pastk = (const float*)d_in[1];
  const float* pastv = (const float*)d_in[2];
  const float* wqkv  = (const float*)d_in[3];
  const float* bqkv  = (const float*)d_in[4];
  const float* wproj = (const float*)d_in[5];
  const float* bproj = (const float*)d_in[6];
  float* out = (float*)d_out;
  char* ws = (char*)d_ws;

  size_t off = 0;
  short* qbuf   = (short*)(ws + off); off += (size_t)BB*NH*NQ*HD*2;          // 1MB
  float* knew   = (float*)(ws + off); off += (size_t)BB*NH*NQ*HD*4;          // 2MB
  float* vnew   = (float*)(ws + off); off += (size_t)BB*NH*NQ*HD*4;          // 2MB
  float* opart  = (float*)(ws + off); off += (size_t)BB*NH*NSPLIT*NQ*HD*4;   // 32MB
  float* mbuf   = (float*)(ws + off); off += (size_t)BB*NH*NSPLIT*NQ*4;      // 512KB
  float* lbuf   = (float*)(ws + off); off += (size_t)BB*NH*NSPLIT*NQ*4;      // 512KB
  float* attnout= (float*)(ws + off); off += (size_t)BB*NQ*DIMC*4;           // 2MB

  // 1) QKV projection: [512,1024] x [1024,3072]
  gemm_k<1><<<(512/64)*(3072/64), 256, 0, stream>>>(
      x, wqkv, bqkv, nullptr, qbuf, knew, vnew, 512, 3072, 1024);
  // 2) split-KV flash attention
  attn_k<<<BB*NH*NSPLIT, 256, 0, stream>>>(
      qbuf, pastk, pastv, knew, vnew, opart, mbuf, lbuf);
  // 3) combine partials
  combine_k<<<BB*NH*NQ/4, 256, 0, stream>>>(opart, mbuf, lbuf, attnout);
  // 4) output projection: [512,1024] x [1024,1024]
  gemm_k<0><<<(512/64)*(1024/64), 256, 0, stream>>>(
      attnout, wproj, bproj, out, nullptr, nullptr, nullptr, 512, 1024, 1024);
}